// Round 6
// baseline (9097.518 us; speedup 1.0000x reference)
//
#include <hip/hip_runtime.h>
#include <math.h>

#define AGENT __HIP_MEMORY_SCOPE_AGENT

constexpr int kNWG   = 32;
constexpr int kTPB   = 256;
constexpr int kD     = 16;    // data dim
constexpr int kH     = 128;   // hidden dim
constexpr int kW     = 256;   // vf mlp width
constexpr int kOut   = 2048;  // D*H
constexpr int kLsig  = 137;
constexpr int kT     = 200001;
constexpr int kNRow  = 101;   // distinct eval times
constexpr int kNEval = 200;
constexpr int SPIN_MAX = 1 << 16;  // session-safety bailout; never hit when healthy

// ---------------- workspace layout ----------------
// float idx: FLAGS 0..31 (u32), IDX 32..132 (int), INV 160..260, YB 288..415,
// T2B 416..4511 (4096 plain floats, gbar-protected, R0 mechanism),
// u64 idx (from ws base): WTAG 2256..4303, RSPTAG 4304..6351
//   each u64 = {epoch tag (hi32), exact f32 payload bits (lo32)} — tag+data one
//   atom, single relaxed AGENT load delivers both. Payload bits UNMODIFIED
//   (bit-exact, unlike the failed parity-LSB variant).
// total = 6352*8 = 50,816 B  (< proven-safe 52,864 B)
constexpr int FLAGS_OFF  = 0;
constexpr int IDX_OFF    = 32;
constexpr int INV_OFF    = 160;
constexpr int YB_OFF     = 288;
constexpr int T2B_OFF    = 416;
constexpr int WTAG_U64   = 2256;
constexpr int RSPTAG_U64 = 4304;

__device__ __forceinline__ float b2f(unsigned short u){
  union { unsigned int i; float f; } v; v.i = ((unsigned int)u) << 16; return v.f;
}
__device__ __forceinline__ unsigned short f2b(float f){ // RNE
  unsigned int x = __float_as_uint(f);
  unsigned int r = x + 0x7fffu + ((x >> 16) & 1u);
  return (unsigned short)(r >> 16);
}
__device__ __forceinline__ float ldf(const void* p, size_t i, bool bf){
  return bf ? b2f(((const unsigned short*)p)[i]) : ((const float*)p)[i];
}
template<bool BF>
__device__ __forceinline__ float ldT(const void* p, size_t i){
  return BF ? b2f(((const unsigned short*)p)[i]) : ((const float*)p)[i];
}
// cross-WG data plane: AGENT-scope relaxed atomics (coherent at IF$).
__device__ __forceinline__ float aload(const float* p){
  return __hip_atomic_load(p, __ATOMIC_RELAXED, AGENT);
}
__device__ __forceinline__ void astore(float* p, float v){
  __hip_atomic_store(p, v, __ATOMIC_RELAXED, AGENT);
}
__device__ __forceinline__ unsigned long long aload64(const unsigned long long* p){
  return __hip_atomic_load(p, __ATOMIC_RELAXED, AGENT);
}
__device__ __forceinline__ void astore64(unsigned long long* p, unsigned long long v){
  __hip_atomic_store(p, v, __ATOMIC_RELAXED, AGENT);
}
__device__ __forceinline__ unsigned long long pk64(unsigned tag, float f){
  return ((unsigned long long)tag << 32) | (unsigned long long)__float_as_uint(f);
}
__device__ __forceinline__ int pairidx(int i, int j){ // i<j, triu_indices(16,1)
  return i*15 - (i*(i-1))/2 + (j - i - 1);
}

// software inter-WG barrier — EXACT round-0-proven mechanism (used 1x/eval for T2)
__device__ __forceinline__ void gbar(unsigned* flags, int g, unsigned epoch, int tid){
  asm volatile("s_waitcnt vmcnt(0)" ::: "memory");
  __syncthreads();
  if (tid == 0)
    __hip_atomic_store(&flags[g], epoch, __ATOMIC_RELAXED, AGENT);
  if (tid < kNWG){
    int spins = 0;
    while (__hip_atomic_load(&flags[tid], __ATOMIC_RELAXED, AGENT) < epoch){
      __builtin_amdgcn_s_sleep(1);
      if (++spins > SPIN_MAX) break;
    }
  }
  __syncthreads();
}

// ---------------- init ----------------
__global__ void cde_init(const void* __restrict__ tsp, const void* __restrict__ x0p,
                         const void* __restrict__ l1wp, const void* __restrict__ l1bp,
                         float* __restrict__ ws)
{
  const int tid = threadIdx.x; // 256 threads
  const bool bf = (((const unsigned*)tsp)[0] != 0u);
  const float ts0 = ldf(tsp, 0, bf);
  const float dt  = (ldf(tsp, kT-1, bf) - ts0) / 100.0f;

  if (tid < kNWG) ((unsigned*)(ws + FLAGS_OFF))[tid] = 0u;
  {
    unsigned long long* tg = ((unsigned long long*)ws) + WTAG_U64;
    for (int i = tid; i < 4096; i += kTPB) tg[i] = 0ULL;   // W + rsp tags -> 0
  }

  if (tid < kNRow){
    float t = ts0;
    for (int i = 0; i < tid; i++) t += dt;       // exact fp32 scan carry
    const int N1 = kT - 1;
    int lo = 0, hi = N1;
    while (lo < hi){
      int mid = (lo + hi) >> 1;
      if (ldf(tsp, 1 + mid, bf) < t) lo = mid + 1; else hi = mid;
    }
    int idx = lo + 1; if (idx > kT-1) idx = kT-1; if (idx < 1) idx = 1;
    ((int*)ws)[IDX_OFF + tid] = idx;
    float w = ldf(tsp, idx, bf) - ldf(tsp, idx-1, bf);
    ws[INV_OFF + tid] = (w > 0.f) ? (1.0f / w) : 0.f;
  }
  if (tid < kH){
    float acc = ldf(l1bp, tid, bf);
    for (int d2 = 0; d2 < kD; d2++) acc += ldf(x0p, d2, bf) * ldf(l1wp, d2*kH + tid, bf);
    ws[YB_OFF + tid] = acc;
  }
}

// ---------------- persistent main kernel ----------------
struct SMem {
  float w3T[64][257];            // w3 cols g*64..+63, transposed, padded
  float w2cT[8][257];            // w2[:, g*8+o] transposed (G5 owner-T2 only)
  alignas(16) float Wt[kD][kH];  // full W = tanh(z3); broadcast/strided reads only
  float T1[kD][257];             // full T1 (emulated locally), padded
  float h1[kW], s1p[kW];
  float h2[kW], s2p[kW];
  float ls[kLsig + 7];
  float y[kH], ymid[kH], k1v[kH];
  float Urow[kW];
  float red[4][64];
  float tanhp[64];
  float b1f[kW], b2f[kW];
  float b3c[64];
  float Acol[kD];
  float lgts[16];
};
static_assert(sizeof(SMem) <= 120*1024, "LDS budget");

// The whole eval loop, templated on dtype so the hot streams have no per-element branch.
template<bool BF>
__device__ void run_loop(SMem& s, const void* logsigp, const void* w1p, const void* w2p,
                         float* ws, int g, int tid, int lane, int wave,
                         float dt, float dth)
{
  unsigned* flags = (unsigned*)(ws + FLAGS_OFF);
  float* T2b = ws + T2B_OFF;
  unsigned long long* wtag   = ((unsigned long long*)ws) + WTAG_U64;
  unsigned long long* rsptag = ((unsigned long long*)ws) + RSPTAG_U64;
  unsigned epoch = 0;

  for (int e = 0; e < kNEval; e++){
    const unsigned tag = (unsigned)(e + 1);
    const int r = (e + 1) >> 1;
    {
      const int idx = ((const int*)ws)[IDX_OFF + r];
      const float inv = ws[INV_OFF + r];
      for (int c = tid; c < kLsig; c += kTPB)
        s.ls[c] = ldT<BF>(logsigp, (size_t)(idx - 1)*kLsig + c) * inv;
    }
    const float* ycur = (e & 1) ? s.ymid : s.y;

    // ---- G1em: z1[n] for ALL n — bit-exact emulation of the owner's
    //      {4-chunk lane partial, 32-lane shuffle tree} reduction ----
    {
      const int n = tid;
      float p[32];
      #pragma unroll
      for (int l = 0; l < 32; l++){
        float a = 0.f;
        #pragma unroll
        for (int jj = 0; jj < 4; jj++)
          a += ycur[jj*32 + l] * ldT<BF>(w1p, (size_t)(jj*32 + l)*kW + n);
        p[l] = a;
      }
      #pragma unroll
      for (int off = 16; off >= 1; off >>= 1){
        #pragma unroll
        for (int l = 0; l < 16; l++)
          if (l < off) p[l] += p[l + off];
      }
      float z = p[0] + s.b1f[n];
      float sg = 1.0f / (1.0f + expf(-z));
      s.h1[n]  = z * sg;
      s.s1p[n] = sg * (1.0f + z*(1.0f - sg));
    }
    __syncthreads();

    // ---- G2em: z2[n] for ALL n — same tree, 8 chunks ----
    {
      const int n = tid;
      float p[32];
      #pragma unroll
      for (int l = 0; l < 32; l++){
        float a = 0.f;
        #pragma unroll
        for (int jj = 0; jj < 8; jj++)
          a += s.h1[jj*32 + l] * ldT<BF>(w2p, (size_t)(jj*32 + l)*kW + n);
        p[l] = a;
      }
      #pragma unroll
      for (int off = 16; off >= 1; off >>= 1){
        #pragma unroll
        for (int l = 0; l < 16; l++)
          if (l < off) p[l] += p[l + off];
      }
      float z = p[0] + s.b2f[n];
      float sg = 1.0f / (1.0f + expf(-z));
      s.h2[n]  = z * sg;
      s.s2p[n] = sg * (1.0f + z*(1.0f - sg));
    }
    __syncthreads();

    // ---- G3: z3 for own 64 cols (R0 verbatim); publish W tagged ----
    {
      float acc = 0.f;
      #pragma unroll 8
      for (int j = 0; j < 64; j++) acc += s.h2[wave*64 + j] * s.w3T[lane][wave*64 + j];
      s.red[wave][lane] = acc;
    }
    __syncthreads();
    if (wave == 0){
      float z3 = s.red[0][lane] + s.red[1][lane] + s.red[2][lane] + s.red[3][lane] + s.b3c[lane];
      float Wv = tanhf(z3);
      s.tanhp[lane] = 1.0f - Wv*Wv;
      astore64(wtag + g*64 + lane, pk64(tag, Wv));   // RENDEZVOUS #1 (tagged)
    }
    {
      unsigned long long v[8];
      #pragma unroll
      for (int j2 = 0; j2 < 8; j2++) v[j2] = aload64(wtag + tid + j2*kTPB);
      #pragma unroll
      for (int j2 = 0; j2 < 8; j2++){
        int sp = 0;
        while ((unsigned)(v[j2] >> 32) != tag){
          __builtin_amdgcn_s_sleep(1);
          v[j2] = aload64(wtag + tid + j2*kTPB);
          if (++sp > SPIN_MAX) break;
        }
        int i = tid + j2*kTPB;
        s.Wt[i>>7][i&127] = __uint_as_float((unsigned)v[j2]);
      }
    }
    __syncthreads();

    // ---- T1em: T1[k][n] for ALL (k,n) — bit-exact emulation of the owner's
    //      {even chain, odd chain, shfl_xor pair-add} then *s1p ----
    {
      const int n = tid;
      float ev[kD], ov[kD];
      #pragma unroll
      for (int k = 0; k < kD; k++){ ev[k] = 0.f; ov[k] = 0.f; }
      const float s1 = s.s1p[n];
      for (int j4 = 0; j4 < 32; j4++){   // j = 4*j4 .. 4*j4+3
        float a0 = ldT<BF>(w1p, (size_t)(4*j4+0)*kW + n);
        float a1 = ldT<BF>(w1p, (size_t)(4*j4+1)*kW + n);
        float a2 = ldT<BF>(w1p, (size_t)(4*j4+2)*kW + n);
        float a3 = ldT<BF>(w1p, (size_t)(4*j4+3)*kW + n);
        #pragma unroll
        for (int k = 0; k < kD; k++){
          float4 wt = *reinterpret_cast<const float4*>(&s.Wt[k][4*j4]); // uniform bcast
          ev[k] += wt.x * a0;   // even j ascending: 4j4, 4j4+2
          ov[k] += wt.y * a1;   // odd  j ascending: 4j4+1, 4j4+3
          ev[k] += wt.z * a2;
          ov[k] += wt.w * a3;
        }
      }
      #pragma unroll
      for (int k = 0; k < kD; k++) s.T1[k][n] = (ev[k] + ov[k]) * s1;
    }
    __syncthreads();

    // ---- G5: owner T2 for own 8 cols (R0 verbatim; s2p now full-indexed) ----
    {
      const int outi = tid >> 1, half = tid & 1;
      const int k = outi >> 3, o = outi & 7;
      float acc = 0.f;
      #pragma unroll 16
      for (int jj = 0; jj < 128; jj++){ int n2 = jj*2 + half; acc += s.T1[k][n2] * s.w2cT[o][n2]; }
      acc += __shfl_xor(acc, 1);
      if (half == 0) astore(T2b + k*kW + g*8 + o, acc * s.s2p[g*8 + o]);
    }
    gbar(flags, g, ++epoch, tid);                    // RENDEZVOUS #2 (proven gbar)

    // ---- G6: Urow for block ig = g>>1; res own cols (R0 verbatim); publish rsp tagged ----
    if (tid < kD){
      const int ig = g >> 1; const int k = tid; float v = 0.f;
      if (k < ig)      v =  s.ls[17 + pairidx(k, ig)];
      else if (k > ig) v = -s.ls[17 + pairidx(ig, k)];
      s.Acol[k] = v;
    }
    __syncthreads();
    {
      float u = 0.f; const int n = tid;
      #pragma unroll
      for (int k2 = 0; k2 < kD; k2++) u += s.Acol[k2] * aload(T2b + k2*kW + n);
      s.Urow[n] = u;
    }
    __syncthreads();
    {
      float acc = 0.f;
      #pragma unroll 8
      for (int j = 0; j < 64; j++) acc += s.Urow[wave*64 + j] * s.w3T[lane][wave*64 + j];
      s.red[wave][lane] = acc;
    }
    __syncthreads();
    if (wave == 0){
      float v = (s.red[0][lane] + s.red[1][lane] + s.red[2][lane] + s.red[3][lane]) * s.tanhp[lane];
      if (g < 2){
        float lin = 0.f; const int h = g*64 + lane;
        #pragma unroll
        for (int k2 = 0; k2 < kD; k2++) lin += s.ls[1 + k2] * s.Wt[k2][h];
        v += lin;
      }
      astore64(rsptag + g*64 + lane, pk64(tag, v));  // RENDEZVOUS #3 (tagged)
    }

    // ---- G7: poll rsp tagged, reduce in R0 order, Heun update ----
    if (tid < kH){
      const int hh = tid >> 6, hl = tid & 63;
      unsigned long long v[kD];
      #pragma unroll
      for (int i2 = 0; i2 < kD; i2++) v[i2] = aload64(rsptag + (2*i2 + hh)*64 + hl);
      #pragma unroll
      for (int i2 = 0; i2 < kD; i2++){
        int sp = 0;
        while ((unsigned)(v[i2] >> 32) != tag){
          __builtin_amdgcn_s_sleep(1);
          v[i2] = aload64(rsptag + (2*i2 + hh)*64 + hl);
          if (++sp > SPIN_MAX) break;
        }
      }
      float rs = 0.f;
      #pragma unroll
      for (int i2 = 0; i2 < kD; i2++) rs += __uint_as_float((unsigned)v[i2]);
      if (!(e & 1)){ s.k1v[tid] = rs; s.ymid[tid] = s.y[tid] + dt * rs; }
      else         { s.y[tid] = s.y[tid] + dth * (s.k1v[tid] + rs); }
    }
    __syncthreads();
  }
}

__global__ __launch_bounds__(kTPB, 1)
void cde_main(const void* __restrict__ tsp, const void* __restrict__ logsigp,
              const void* __restrict__ w1p, const void* __restrict__ b1p,
              const void* __restrict__ w2p, const void* __restrict__ b2p,
              const void* __restrict__ w3p, const void* __restrict__ b3p,
              const void* __restrict__ l2wp, const void* __restrict__ l2bp,
              float* __restrict__ ws, void* __restrict__ outp)
{
  __shared__ SMem s;
  const int g = blockIdx.x, tid = threadIdx.x;
  const int lane = tid & 63, wave = tid >> 6;
  const bool bf = (((const unsigned*)tsp)[0] != 0u);

  // ---- stage into LDS (one-time) ----
  for (int i = tid; i < 8*kW; i += kTPB){ int o = i>>8, n = i&255; s.w2cT[o][n] = ldf(w2p, (size_t)n*kW + g*8 + o, bf); }
  for (int i = tid; i < 64*kW; i += kTPB){ int n = i>>6, c = i&63;  s.w3T[c][n]  = ldf(w3p, (size_t)n*kOut + g*64 + c, bf); }
  s.b1f[tid] = ldf(b1p, tid, bf);
  s.b2f[tid] = ldf(b2p, tid, bf);
  if (tid < 64) s.b3c[tid] = ldf(b3p, g*64 + tid, bf);
  if (tid < kH) s.y[tid] = ws[YB_OFF + tid];
  const float dt  = (ldf(tsp, kT-1, bf) - ldf(tsp, 0, bf)) / 100.0f;
  const float dth = 0.5f * dt;
  __syncthreads();

  if (bf) run_loop<true >(s, logsigp, w1p, w2p, ws, g, tid, lane, wave, dt, dth);
  else    run_loop<false>(s, logsigp, w1p, w2p, ws, g, tid, lane, wave, dt, dth);

  // ---- classification head + softmax (WG0), dtype-matched output ----
  if (g == 0){
    if (tid < 10){
      float acc = ldf(l2bp, tid, bf);
      for (int h = 0; h < kH; h++) acc += s.y[h] * ldf(l2wp, (size_t)h*10 + tid, bf);
      s.lgts[tid] = acc;
    }
    __syncthreads();
    if (tid < 10){
      float m = s.lgts[0];
      #pragma unroll
      for (int i2 = 1; i2 < 10; i2++) m = fmaxf(m, s.lgts[i2]);
      float num = expf(s.lgts[tid] - m);
      float den = 0.f;
      #pragma unroll
      for (int i2 = 0; i2 < 10; i2++) den += expf(s.lgts[i2] - m);
      float v = num / den;
      if (bf) ((unsigned short*)outp)[tid] = f2b(v);
      else    ((float*)outp)[tid] = v;
    }
  }
}

extern "C" void kernel_launch(void* const* d_in, const int* in_sizes, int n_in,
                              void* d_out, int out_size, void* d_ws, size_t ws_size,
                              hipStream_t stream)
{
  const void* ts   = d_in[0];
  const void* lsig = d_in[1];
  const void* x0   = d_in[2];
  // d_in[3] = intervals == ts
  const void* l1w  = d_in[4];
  const void* l1b  = d_in[5];
  const void* w1   = d_in[6];
  const void* b1   = d_in[7];
  const void* w2   = d_in[8];
  const void* b2   = d_in[9];
  const void* w3   = d_in[10];
  const void* b3   = d_in[11];
  const void* l2w  = d_in[12];
  const void* l2b  = d_in[13];
  float* ws = (float*)d_ws;

  hipLaunchKernelGGL(cde_init, dim3(1), dim3(kTPB), 0, stream, ts, x0, l1w, l1b, ws);
  hipLaunchKernelGGL(cde_main, dim3(kNWG), dim3(kTPB), 0, stream,
                     ts, lsig, w1, b1, w2, b2, w3, b3, l2w, l2b, ws, d_out);
}

// Round 7
// 5560.146 us; speedup vs baseline: 1.6362x; 1.6362x over previous
//
#include <hip/hip_runtime.h>
#include <math.h>

#define AGENT __HIP_MEMORY_SCOPE_AGENT

constexpr int kNWG   = 32;
constexpr int kTPB   = 256;
constexpr int kD     = 16;    // data dim
constexpr int kH     = 128;   // hidden dim
constexpr int kW     = 256;   // vf mlp width
constexpr int kOut   = 2048;  // D*H
constexpr int kLsig  = 137;
constexpr int kT     = 200001;
constexpr int kNRow  = 101;   // distinct eval times
constexpr int kNEval = 200;
constexpr int SPIN_MAX = 1 << 16;  // session-safety bailout; never hit when healthy

// ---------------- workspace layouts ----------------
// Common misc (floats): FLAGS 0..31 (u32), IDX 32..132 (int), INV 160..260,
//                       YB 288..415.
// SLOW layout (== round-0 proven, 13216 floats = 52,864 B): all six buffers
// plain f32, every phase gbar-synced.
constexpr int FLAGS_OFF = 0;
constexpr int IDX_OFF   = 32;
constexpr int INV_OFF   = 160;
constexpr int YB_OFF    = 288;
constexpr int S_H1B = 416, S_H2B = 672, S_WB = 928, S_T1B = 2976, S_T2B = 7072, S_RSP = 11168;
// FAST layout (69,248 B, used only when ws_size allows): h1/h2/T1/T2 plain +
// gbar; W and rsp transported as u64 {epoch tag | exact f32 bits} atoms
// (single relaxed AGENT load delivers tag+data — R6-proven bit-exact).
constexpr int F_H1B = 416, F_H2B = 672, F_T1B = 928, F_T2B = 5024;  // plain floats end 9120
constexpr int F_WTAG = 4560, F_RSPTAG = 6608;   // u64 indices from ws base; end 8656
constexpr size_t F_BYTES = 69248;

__device__ __forceinline__ float b2f(unsigned short u){
  union { unsigned int i; float f; } v; v.i = ((unsigned int)u) << 16; return v.f;
}
__device__ __forceinline__ unsigned short f2b(float f){ // RNE
  unsigned int x = __float_as_uint(f);
  unsigned int r = x + 0x7fffu + ((x >> 16) & 1u);
  return (unsigned short)(r >> 16);
}
__device__ __forceinline__ float ldf(const void* p, size_t i, bool bf){
  return bf ? b2f(((const unsigned short*)p)[i]) : ((const float*)p)[i];
}
// cross-WG data plane: AGENT-scope relaxed atomics (coherent at IF$).
__device__ __forceinline__ float aload(const float* p){
  return __hip_atomic_load(p, __ATOMIC_RELAXED, AGENT);
}
__device__ __forceinline__ void astore(float* p, float v){
  __hip_atomic_store(p, v, __ATOMIC_RELAXED, AGENT);
}
__device__ __forceinline__ unsigned long long aload64(const unsigned long long* p){
  return __hip_atomic_load(p, __ATOMIC_RELAXED, AGENT);
}
__device__ __forceinline__ void astore64(unsigned long long* p, unsigned long long v){
  __hip_atomic_store(p, v, __ATOMIC_RELAXED, AGENT);
}
__device__ __forceinline__ unsigned long long pk64(unsigned tag, float f){
  return ((unsigned long long)tag << 32) | (unsigned long long)__float_as_uint(f);
}
__device__ __forceinline__ int pairidx(int i, int j){ // i<j, triu_indices(16,1)
  return i*15 - (i*(i-1))/2 + (j - i - 1);
}

// software inter-WG barrier — round-0-proven mechanism
__device__ __forceinline__ void gbar(unsigned* flags, int g, unsigned epoch, int tid){
  asm volatile("s_waitcnt vmcnt(0)" ::: "memory");
  __syncthreads();
  if (tid == 0)
    __hip_atomic_store(&flags[g], epoch, __ATOMIC_RELAXED, AGENT);
  if (tid < kNWG){
    int spins = 0;
    while (__hip_atomic_load(&flags[tid], __ATOMIC_RELAXED, AGENT) < epoch){
      __builtin_amdgcn_s_sleep(1);
      if (++spins > SPIN_MAX) break;
    }
  }
  __syncthreads();
}

// ---------------- init ----------------
__global__ void cde_init(const void* __restrict__ tsp, const void* __restrict__ x0p,
                         const void* __restrict__ l1wp, const void* __restrict__ l1bp,
                         float* __restrict__ ws, int fast)
{
  const int tid = threadIdx.x; // 128 threads
  const bool bf = (((const unsigned*)tsp)[0] != 0u);  // fp32 ts[0]==0.0f -> word0==0
  const float ts0 = ldf(tsp, 0, bf);
  const float dt  = (ldf(tsp, kT-1, bf) - ts0) / 100.0f;  // fp32, same as reference

  if (tid < kNWG) ((unsigned*)(ws + FLAGS_OFF))[tid] = 0u;
  if (fast){
    unsigned long long* tg = ((unsigned long long*)ws) + F_WTAG;
    for (int i = tid; i < 4096; i += 128) tg[i] = 0ULL;   // W + rsp tags -> 0
  }

  if (tid < kNRow){
    // exact fp32 left-to-right accumulation, matching the reference scan carry
    float t = ts0;
    for (int i = 0; i < tid; i++) t += dt;
    // searchsorted(side=left) over ts[1:]: first pos with a[pos] >= t
    const int N1 = kT - 1;
    int lo = 0, hi = N1;
    while (lo < hi){
      int mid = (lo + hi) >> 1;
      if (ldf(tsp, 1 + mid, bf) < t) lo = mid + 1; else hi = mid;
    }
    int idx = lo + 1; if (idx > kT-1) idx = kT-1; if (idx < 1) idx = 1;
    ((int*)ws)[IDX_OFF + tid] = idx;
    float w = ldf(tsp, idx, bf) - ldf(tsp, idx-1, bf);
    ws[INV_OFF + tid] = (w > 0.f) ? (1.0f / w) : 0.f;
  }
  if (tid < kH){
    float acc = ldf(l1bp, tid, bf);
    for (int d2 = 0; d2 < kD; d2++) acc += ldf(x0p, d2, bf) * ldf(l1wp, d2*kH + tid, bf);
    ws[YB_OFF + tid] = acc;   // y0 = x0 @ l1_w + l1_b
  }
}

// ---------------- persistent main kernel ----------------
struct SMem {
  float w3T[64][257];   // w3 cols g*64..+63, transposed, padded   (~64.2 KB)
  float w1cT[8][129];   // w1[:, g*8+o] transposed, padded
  float w2cT[8][257];
  float Wt[kD][129];    // full W = tanh(z3), padded
  float T1[kD][257];    // full T1s, padded
  float h1[kW], h2[kW];
  float ls[kLsig + 7];
  float y[kH], ymid[kH], k1v[kH];
  float Urow[kW];
  float red[4][64];
  float tanhp[64];
  float s1p[8], s2p[8], b1c[8], b2c[8];
  float b3c[64];
  float Acol[kD];
  float lgts[16];
};
static_assert(sizeof(SMem) <= 120*1024, "LDS budget");

__global__ __launch_bounds__(kTPB, 1)
void cde_main(const void* __restrict__ tsp, const void* __restrict__ logsigp,
              const void* __restrict__ w1p, const void* __restrict__ b1p,
              const void* __restrict__ w2p, const void* __restrict__ b2p,
              const void* __restrict__ w3p, const void* __restrict__ b3p,
              const void* __restrict__ l2wp, const void* __restrict__ l2bp,
              float* __restrict__ ws, void* __restrict__ outp, int fast)
{
  __shared__ SMem s;
  const int g = blockIdx.x, tid = threadIdx.x;
  const int lane = tid & 63, wave = tid >> 6;
  const bool bf = (((const unsigned*)tsp)[0] != 0u);
  unsigned* flags = (unsigned*)(ws + FLAGS_OFF);
  float* h1b = ws + (fast ? F_H1B : S_H1B);
  float* h2b = ws + (fast ? F_H2B : S_H2B);
  float* T1b = ws + (fast ? F_T1B : S_T1B);
  float* T2b = ws + (fast ? F_T2B : S_T2B);
  float* Wb  = ws + S_WB;    // slow path only
  float* rsp = ws + S_RSP;   // slow path only
  unsigned long long* wtag   = ((unsigned long long*)ws) + F_WTAG;    // fast only
  unsigned long long* rsptag = ((unsigned long long*)ws) + F_RSPTAG;  // fast only

  // ---- stage weights into LDS (one-time) ----
  for (int i = tid; i < 8*kH; i += kTPB){ int o = i>>7, j = i&127; s.w1cT[o][j] = ldf(w1p, (size_t)j*kW + g*8 + o, bf); }
  for (int i = tid; i < 8*kW; i += kTPB){ int o = i>>8, n = i&255; s.w2cT[o][n] = ldf(w2p, (size_t)n*kW + g*8 + o, bf); }
  for (int i = tid; i < 64*kW; i += kTPB){ int n = i>>6, c = i&63;  s.w3T[c][n]  = ldf(w3p, (size_t)n*kOut + g*64 + c, bf); }
  if (tid < 8){ s.b1c[tid] = ldf(b1p, g*8 + tid, bf); s.b2c[tid] = ldf(b2p, g*8 + tid, bf); }
  if (tid < 64) s.b3c[tid] = ldf(b3p, g*64 + tid, bf);
  if (tid < kH) s.y[tid] = ws[YB_OFF + tid];
  const float dt  = (ldf(tsp, kT-1, bf) - ldf(tsp, 0, bf)) / 100.0f;
  const float dth = 0.5f * dt;
  __syncthreads();

  unsigned epoch = 0;

  for (int e = 0; e < kNEval; e++){
    const unsigned tag = (unsigned)(e + 1);   // fast-path epoch tag
    const int r = (e + 1) >> 1;               // e=2s -> t_s, e=2s+1 -> t_{s+1}
    {
      const int idx = ((const int*)ws)[IDX_OFF + r];
      const float inv = ws[INV_OFF + r];
      for (int c = tid; c < kLsig; c += kTPB)
        s.ls[c] = ldf(logsigp, (size_t)(idx - 1)*kLsig + c, bf) * inv;  // fold 1/width
    }
    __syncthreads();
    const float* ycur = (e & 1) ? s.ymid : s.y;

    // ---- G1: z1[n] for this WG's 8 cols; h1 -> bcast, silu' local ----
    {
      const int o = tid >> 5, l = tid & 31;
      float acc = 0.f;
      #pragma unroll
      for (int jj = 0; jj < 4; jj++){ int j = jj*32 + l; acc += ycur[j] * s.w1cT[o][j]; }
      #pragma unroll
      for (int off = 16; off; off >>= 1) acc += __shfl_down(acc, off, 32);
      if (l == 0){
        float z = acc + s.b1c[o];
        float sg = 1.0f / (1.0f + expf(-z));
        s.s1p[o] = sg * (1.0f + z*(1.0f - sg));
        astore(h1b + g*8 + o, z * sg);
      }
    }
    gbar(flags, g, ++epoch, tid);
    s.h1[tid] = aload(h1b + tid);
    __syncthreads();

    // ---- G2: z2[n'] ----
    {
      const int o = tid >> 5, l = tid & 31;
      float acc = 0.f;
      #pragma unroll
      for (int jj = 0; jj < 8; jj++){ int j = jj*32 + l; acc += s.h1[j] * s.w2cT[o][j]; }
      #pragma unroll
      for (int off = 16; off; off >>= 1) acc += __shfl_down(acc, off, 32);
      if (l == 0){
        float z = acc + s.b2c[o];
        float sg = 1.0f / (1.0f + expf(-z));
        s.s2p[o] = sg * (1.0f + z*(1.0f - sg));
        astore(h2b + g*8 + o, z * sg);
      }
    }
    gbar(flags, g, ++epoch, tid);
    s.h2[tid] = aload(h2b + tid);
    __syncthreads();

    // ---- G3: z3 for 64 owned cols from LDS w3T; W=tanh handoff ----
    {
      float acc = 0.f;
      #pragma unroll 8
      for (int j = 0; j < 64; j++) acc += s.h2[wave*64 + j] * s.w3T[lane][wave*64 + j];
      s.red[wave][lane] = acc;
    }
    __syncthreads();
    if (wave == 0){
      float z3 = s.red[0][lane] + s.red[1][lane] + s.red[2][lane] + s.red[3][lane] + s.b3c[lane];
      float Wv = tanhf(z3);
      s.tanhp[lane] = 1.0f - Wv*Wv;
      if (fast) astore64(wtag + g*64 + lane, pk64(tag, Wv));  // 1-RTT tagged handoff
      else      astore(Wb + g*64 + lane, Wv);
    }
    if (fast){
      unsigned long long pv[8];
      #pragma unroll
      for (int j2 = 0; j2 < 8; j2++) pv[j2] = aload64(wtag + tid + j2*kTPB);
      #pragma unroll
      for (int j2 = 0; j2 < 8; j2++){
        int sp = 0;
        while ((unsigned)(pv[j2] >> 32) != tag){
          __builtin_amdgcn_s_sleep(1);
          pv[j2] = aload64(wtag + tid + j2*kTPB);
          if (++sp > SPIN_MAX) break;
        }
        int i = tid + j2*kTPB;
        s.Wt[i>>7][i&127] = __uint_as_float((unsigned)pv[j2]);
      }
    } else {
      gbar(flags, g, ++epoch, tid);
      for (int i = tid; i < kD*kH; i += kTPB){ int k = i>>7, h = i&127; s.Wt[k][h] = aload(Wb + i); }
    }
    __syncthreads();

    // ---- G4: T1s[k][n] = s1'[n] * (W_k @ w1)[n], n in owned 8 cols ----
    {
      const int outi = tid >> 1, half = tid & 1;
      const int k = outi >> 3, o = outi & 7;
      float acc = 0.f;
      #pragma unroll
      for (int jj = 0; jj < 64; jj++){ int j = jj*2 + half; acc += s.Wt[k][j] * s.w1cT[o][j]; }
      acc += __shfl_xor(acc, 1);
      if (half == 0) astore(T1b + k*kW + g*8 + o, acc * s.s1p[o]);
    }
    gbar(flags, g, ++epoch, tid);
    for (int i = tid; i < kD*kW; i += kTPB){ int k = i>>8, n = i&255; s.T1[k][n] = aload(T1b + i); }
    __syncthreads();

    // ---- G5: T2s[k][n'] = s2'[n'] * (T1s[k] @ w2)[n'] ----
    {
      const int outi = tid >> 1, half = tid & 1;
      const int k = outi >> 3, o = outi & 7;
      float acc = 0.f;
      #pragma unroll 16
      for (int jj = 0; jj < 128; jj++){ int n = jj*2 + half; acc += s.T1[k][n] * s.w2cT[o][n]; }
      acc += __shfl_xor(acc, 1);
      if (half == 0) astore(T2b + k*kW + g*8 + o, acc * s.s2p[o]);
    }
    gbar(flags, g, ++epoch, tid);

    // ---- G6: U row for block i = g>>1; bracket (+ linear for g<2) via LDS w3T ----
    if (tid < kD){
      const int ig = g >> 1; const int k = tid; float v = 0.f;
      if (k < ig)      v =  s.ls[17 + pairidx(k, ig)];
      else if (k > ig) v = -s.ls[17 + pairidx(ig, k)];
      s.Acol[k] = v;
    }
    __syncthreads();
    {
      float u = 0.f; const int n = tid;
      #pragma unroll
      for (int k2 = 0; k2 < kD; k2++) u += s.Acol[k2] * aload(T2b + k2*kW + n);
      s.Urow[n] = u;
    }
    __syncthreads();
    {
      float acc = 0.f;
      #pragma unroll 8
      for (int j = 0; j < 64; j++) acc += s.Urow[wave*64 + j] * s.w3T[lane][wave*64 + j];
      s.red[wave][lane] = acc;
    }
    __syncthreads();
    if (wave == 0){
      float v = (s.red[0][lane] + s.red[1][lane] + s.red[2][lane] + s.red[3][lane]) * s.tanhp[lane];
      if (g < 2){   // block i=0 owners add the linear term ls1 @ W for their h-half
        float lin = 0.f; const int h = g*64 + lane;
        #pragma unroll
        for (int k2 = 0; k2 < kD; k2++) lin += s.ls[1 + k2] * s.Wt[k2][h];
        v += lin;
      }
      if (fast) astore64(rsptag + g*64 + lane, pk64(tag, v));  // 1-RTT tagged handoff
      else      astore(rsp + g*64 + lane, v);
    }
    if (!fast) gbar(flags, g, ++epoch, tid);

    // ---- G7: gather res partials, Heun update (redundant in every WG) ----
    if (tid < kH){
      const int hh = tid >> 6, hl = tid & 63;
      float rs = 0.f;
      if (fast){
        unsigned long long pv[kD];
        #pragma unroll
        for (int i2 = 0; i2 < kD; i2++) pv[i2] = aload64(rsptag + (2*i2 + hh)*64 + hl);
        #pragma unroll
        for (int i2 = 0; i2 < kD; i2++){
          int sp = 0;
          while ((unsigned)(pv[i2] >> 32) != tag){
            __builtin_amdgcn_s_sleep(1);
            pv[i2] = aload64(rsptag + (2*i2 + hh)*64 + hl);
            if (++sp > SPIN_MAX) break;
          }
        }
        #pragma unroll
        for (int i2 = 0; i2 < kD; i2++) rs += __uint_as_float((unsigned)pv[i2]);
      } else {
        #pragma unroll
        for (int i2 = 0; i2 < kD; i2++) rs += aload(rsp + (2*i2 + hh)*64 + hl);
      }
      if (!(e & 1)){ s.k1v[tid] = rs; s.ymid[tid] = s.y[tid] + dt * rs; }
      else         { s.y[tid] = s.y[tid] + dth * (s.k1v[tid] + rs); }
    }
    __syncthreads();
  }

  // ---- classification head + softmax (WG0), dtype-matched output ----
  if (g == 0){
    if (tid < 10){
      float acc = ldf(l2bp, tid, bf);
      for (int h = 0; h < kH; h++) acc += s.y[h] * ldf(l2wp, (size_t)h*10 + tid, bf);
      s.lgts[tid] = acc;
    }
    __syncthreads();
    if (tid < 10){
      float m = s.lgts[0];
      #pragma unroll
      for (int i2 = 1; i2 < 10; i2++) m = fmaxf(m, s.lgts[i2]);
      float num = expf(s.lgts[tid] - m);
      float den = 0.f;
      #pragma unroll
      for (int i2 = 0; i2 < 10; i2++) den += expf(s.lgts[i2] - m);
      float v = num / den;
      if (bf) ((unsigned short*)outp)[tid] = f2b(v);
      else    ((float*)outp)[tid] = v;
    }
  }
}

extern "C" void kernel_launch(void* const* d_in, const int* in_sizes, int n_in,
                              void* d_out, int out_size, void* d_ws, size_t ws_size,
                              hipStream_t stream)
{
  const void* ts   = d_in[0];
  const void* lsig = d_in[1];
  const void* x0   = d_in[2];
  // d_in[3] = intervals == ts
  const void* l1w  = d_in[4];
  const void* l1b  = d_in[5];
  const void* w1   = d_in[6];
  const void* b1   = d_in[7];
  const void* w2   = d_in[8];
  const void* b2   = d_in[9];
  const void* w3   = d_in[10];
  const void* b3   = d_in[11];
  const void* l2w  = d_in[12];
  const void* l2b  = d_in[13];
  float* ws = (float*)d_ws;
  const int fast = (ws_size >= F_BYTES) ? 1 : 0;  // runtime layout choice, zero risk

  hipLaunchKernelGGL(cde_init, dim3(1), dim3(128), 0, stream, ts, x0, l1w, l1b, ws, fast);
  hipLaunchKernelGGL(cde_main, dim3(kNWG), dim3(kTPB), 0, stream,
                     ts, lsig, w1, b1, w2, b2, w3, b3, l2w, l2b, ws, d_out, fast);
}